// Round 2
// baseline (109.085 us; speedup 1.0000x reference)
//
#include <hip/hip_runtime.h>
#include <hip/hip_fp8.h>

// Problem constants (features: (16, 1024, 512) fp32)
#define B_ 16
#define T_ 1024
#define D_ 512
#define EPS_ 1e-8f
#define SCALE2 20.609929155566063f   // (1/0.07) * log2(e): logits in base-2 domain
#define LN2_ 0.6931471805599453f

#define BT 64                        // tile side per wave
#define NB 16                        // T_/BT block-rows per batch
#define NPAIR (NB * (NB + 1) / 2)    // 136 upper-triangle pairs
#define SCL 0x7B7B7B7B               // E8M0 2^-4 in every byte (opsel-immune)

typedef __attribute__((ext_vector_type(8))) int   int8v;
typedef __attribute__((ext_vector_type(4))) float floatx4;

__device__ __forceinline__ unsigned char f2e4m3(float x) {
    __hip_fp8_e4m3 q(x);                       // OCP e4m3fn, HW RNE on gfx950
    return (unsigned char)q.__x;
}

// ---------------- row L2-normalize -> fp8 e4m3 (x16), fused zero-init --------
// Stores 16*n_i in e4m3 (elements ~N(0,0.7): clear of subnormal coarseness);
// the MFMA block-scales of 2^-4 * 2^-4 restore the true product.
__global__ __launch_bounds__(256) void norm_kernel(const float* __restrict__ f,
                                                   unsigned char* __restrict__ nrm,
                                                   float* __restrict__ rs_g,
                                                   float* __restrict__ rp_g,
                                                   float* __restrict__ out) {
    const int gi = blockIdx.x * 256 + threadIdx.x;
    if (gi < B_ * T_) { rs_g[gi] = 0.0f; rp_g[gi] = 0.0f; }
    if (gi == 0) out[0] = 0.0f;

    const int row  = blockIdx.x * 4 + (threadIdx.x >> 6);
    const int lane = threadIdx.x & 63;
    const size_t off = (size_t)row * D_ + lane * 8;
    const float4 v0 = *(const float4*)(f + off);
    const float4 v1 = *(const float4*)(f + off + 4);
    float ss = v0.x*v0.x + v0.y*v0.y + v0.z*v0.z + v0.w*v0.w
             + v1.x*v1.x + v1.y*v1.y + v1.z*v1.z + v1.w*v1.w;
    #pragma unroll
    for (int o = 32; o >= 1; o >>= 1) ss += __shfl_xor(ss, o, 64);
    const float sc = 16.0f / fmaxf(sqrtf(ss), EPS_);   // pre-scale by 16
    unsigned int w0 =  (unsigned int)f2e4m3(v0.x*sc)
                    | ((unsigned int)f2e4m3(v0.y*sc) << 8)
                    | ((unsigned int)f2e4m3(v0.z*sc) << 16)
                    | ((unsigned int)f2e4m3(v0.w*sc) << 24);
    unsigned int w1 =  (unsigned int)f2e4m3(v1.x*sc)
                    | ((unsigned int)f2e4m3(v1.y*sc) << 8)
                    | ((unsigned int)f2e4m3(v1.z*sc) << 16)
                    | ((unsigned int)f2e4m3(v1.w*sc) << 24);
    uint2 w; w.x = w0; w.y = w1;
    *(uint2*)(nrm + (size_t)row * D_ + lane * 8) = w;   // 8 fp8 bytes/lane
}

// ---------------- MX-fp8 MFMA sim-GEMM: symmetric pairs, 1 wave = 64x64 ------
// v2: no LDS, no barriers. nrm is 8.4 MB total and XCD-pinned (~1 MB/XCD) ->
// fully L2-resident, so staging through LDS only added vmcnt(0)+barrier drains
// at 1.25 waves/SIMD occupancy. Fragments load straight global->VGPR:
// A-frag for lane (m = l&15, kq = l>>4) is 32 contiguous bytes of row
// t0+mi*16+m at byte offset kq*32 + kit*128 -> one int8v load (2x dwordx4).
// Depth-2 kit double-buffer; compiler emits counted vmcnt per register dep.
// Both block-scales = 2^-4 (data x16). C/D layout: shape-determined, identical
// to bf16 16x16 (col=lane&15, row=(lane>>4)*4+reg) -> verified epilogue reused.
__global__ __launch_bounds__(64, 2) void loss_kernel(const unsigned char* __restrict__ nrm,
                                                     float* __restrict__ rs_g,
                                                     float* __restrict__ rp_g) {
    const int slot = blockIdx.x & 15;
    int u = blockIdx.x >> 4;                        // pair index 0..135
    const int b = ((slot & 7) << 1) | (slot >> 3);  // XCD-pinned batches
    int bi = 0, rem = NB;
    while (u >= rem) { u -= rem; --rem; ++bi; }
    const int bj   = bi + u;
    const bool diag = (bi == bj);
    const bool near = (bj - bi) <= 1;               // tiles that can hold j==t+1

    const int t0 = bi * BT;
    const int j0 = bj * BT;
    const char* base = (const char*)(nrm + (size_t)b * T_ * D_);  // row = 512 B

    const int l  = threadIdx.x & 63;
    const int m  = l & 15;
    const int kq = l >> 4;

    const char* pA[4];
    const char* pB[4];
    #pragma unroll
    for (int i = 0; i < 4; ++i) {
        pA[i] = base + (size_t)(t0 + i * 16 + m) * 512 + kq * 32;
        pB[i] = base + (size_t)(j0 + i * 16 + m) * 512 + kq * 32;   // diag: == pA (L1-hit)
    }

    floatx4 acc[4][4] = {};
    int8v a0[4], b0[4], a1[4], b1[4];

    // load one kit (K=128) of A and B fragments into (dA, dB)
#define LK(dA, dB, kk) do {                                            \
    _Pragma("unroll")                                                  \
    for (int i_ = 0; i_ < 4; ++i_)                                     \
        dA[i_] = *(const int8v*)(pA[i_] + (kk) * 128);                 \
    _Pragma("unroll")                                                  \
    for (int i_ = 0; i_ < 4; ++i_)                                     \
        dB[i_] = *(const int8v*)(pB[i_] + (kk) * 128);                 \
} while (0)

    // 16 MFMAs of one kit
#define MM(aF, bF) do {                                                \
    _Pragma("unroll")                                                  \
    for (int mi_ = 0; mi_ < 4; ++mi_)                                  \
        _Pragma("unroll")                                              \
        for (int ni_ = 0; ni_ < 4; ++ni_)                              \
            acc[mi_][ni_] = __builtin_amdgcn_mfma_scale_f32_16x16x128_f8f6f4( \
                aF[mi_], bF[ni_], acc[mi_][ni_],                       \
                0, 0,              /* cbsz=fp8(e4m3), blgp=fp8(e4m3) */ \
                0, SCL,            /* opsel_a, scale_a (2^-4)        */ \
                0, SCL);           /* opsel_b, scale_b               */ \
} while (0)

    LK(a0, b0, 0);          // kits 0 and 1 in flight
    LK(a1, b1, 1);
    MM(a0, b0);             // kit 0 (loads for kit 2 issue behind its mfmas)
    LK(a0, b0, 2);
    MM(a1, b1);             // kit 1 overlaps kit-2 load latency
    LK(a1, b1, 3);
    MM(a0, b0);             // kit 2 overlaps kit-3 load latency
    MM(a1, b1);             // kit 3
#undef LK
#undef MM

    // Epilogue. C/D layout (shape-determined, m89/m121-128): col = lane&15,
    // row = (lane>>4)*4 + reg. Identical to the verified bf16 epilogue.
    const int lrow = l >> 4;
    const int lcol = l & 15;
    const int bT   = b * T_;
    float cs[4] = {0.f, 0.f, 0.f, 0.f};   // per-ni column partials (off-diag)

    #pragma unroll
    for (int mi = 0; mi < 4; ++mi) {
        #pragma unroll
        for (int rg = 0; rg < 4; ++rg) {
            const int t = t0 + mi * 16 + lrow * 4 + rg;
            float rsum = 0.f;
            #pragma unroll
            for (int ni = 0; ni < 4; ++ni) {
                const int j  = j0 + ni * 16 + lcol;
                const float s2 = acc[mi][ni][rg] * SCALE2;       // base-2 logit
                const float e  = exp2f(s2);
                if (j < t - 1 || j > t + 1) { rsum += e; cs[ni] += e; }
                if (near && j == t + 1) atomicAdd(&rp_g[bT + t], s2);  // unique owner
            }
            #pragma unroll
            for (int o = 8; o >= 1; o >>= 1) rsum += __shfl_xor(rsum, o, 64);
            if (lcol == 0) atomicAdd(&rs_g[bT + t], rsum);
        }
    }
    if (!diag) {  // column sums: anchors j in J, negatives t in I (mask symmetric)
        #pragma unroll
        for (int ni = 0; ni < 4; ++ni) {
            float c = cs[ni];
            c += __shfl_xor(c, 16, 64);
            c += __shfl_xor(c, 32, 64);
            if (lrow == 0)
                atomicAdd(&rs_g[bT + j0 + ni * 16 + lcol], c);
        }
    }
}

// ---------------- finalize: loss per (b,t), mean (base-2 domain) -------------
__global__ __launch_bounds__(256) void fin_kernel(const float* __restrict__ rs_g,
                                                  const float* __restrict__ rp_g,
                                                  float* __restrict__ out) {
    const int idx = blockIdx.x * 256 + threadIdx.x;
    float v = 0.0f;
    if (idx < B_ * T_) {
        const int t = idx & (T_ - 1);
        if (t >= 1 && t <= T_ - 2) {
            const float p2 = rp_g[idx];           // pos logit * log2e
            const float s  = rs_g[idx];           // sum_neg 2^logit2
            v = (log2f(exp2f(p2) + s) - p2) * LN2_;
        }
    }
    #pragma unroll
    for (int o = 32; o >= 1; o >>= 1) v += __shfl_xor(v, o, 64);
    __shared__ float ws_[4];
    if ((threadIdx.x & 63) == 0) ws_[threadIdx.x >> 6] = v;
    __syncthreads();
    if (threadIdx.x == 0) {
        const float scale = 1.0f / (float)(B_ * (T_ - 2));
        atomicAdd(out, (ws_[0] + ws_[1] + ws_[2] + ws_[3]) * scale);
    }
}

extern "C" void kernel_launch(void* const* d_in, const int* in_sizes, int n_in,
                              void* d_out, int out_size, void* d_ws, size_t ws_size,
                              hipStream_t stream) {
    const float* feat = (const float*)d_in[0];
    float* out = (float*)d_out;

    // ws layout: nrm (fp8, B*T*D bytes = 8 MB) | rs (B*T f32) | rp (B*T f32)
    unsigned char* nrm = (unsigned char*)d_ws;
    float* rs_g = (float*)((char*)d_ws + (size_t)B_ * T_ * D_);
    float* rp_g = rs_g + B_ * T_;

    norm_kernel<<<B_ * T_ / 4, 256, 0, stream>>>(feat, nrm, rs_g, rp_g, out);
    loss_kernel<<<NPAIR * B_, 64, 0, stream>>>(nrm, rs_g, rp_g);
    fin_kernel<<<(B_ * T_ + 255) / 256, 256, 0, stream>>>(rs_g, rp_g, out);
}

// Round 4
// 93.241 us; speedup vs baseline: 1.1699x; 1.1699x over previous
//
#include <hip/hip_runtime.h>
#include <hip/hip_fp8.h>

// Problem constants (features: (16, 1024, 512) fp32)
#define B_ 16
#define T_ 1024
#define D_ 512
#define EPS_ 1e-8f
#define SCALE2 20.609929155566063f   // (1/0.07) * log2(e): logits in base-2 domain
#define LN2_ 0.6931471805599453f

#define BT2 128                      // tile side per 4-wave block
#define NB2 8                        // T_/BT2 block-rows per batch
#define NPAIR2 (NB2 * (NB2 + 1) / 2) // 36 upper-triangle pairs
#define NKIT 4                       // D_/128 K-iterations (K=128 per MFMA)
#define SCL 0x7B7B7B7B               // E8M0 2^-4 in every byte (opsel-immune)

typedef __attribute__((ext_vector_type(4))) int   int4v;
typedef __attribute__((ext_vector_type(8))) int   int8v;
typedef __attribute__((ext_vector_type(4))) float floatx4;

typedef __attribute__((address_space(1))) const unsigned int g_u32;
typedef __attribute__((address_space(3))) unsigned int l_u32;

__device__ __forceinline__ void glds16(const void* g, void* l) {
    __builtin_amdgcn_global_load_lds((g_u32*)g, (l_u32*)l, 16, 0, 0);
}

__device__ __forceinline__ unsigned char f2e4m3(float x) {
    __hip_fp8_e4m3 q(x);                       // OCP e4m3fn, HW RNE on gfx950
    return (unsigned char)q.__x;
}

// ---------------- row L2-normalize -> fp8 e4m3 (x16), fused zero-init --------
__global__ __launch_bounds__(256) void norm_kernel(const float* __restrict__ f,
                                                   unsigned char* __restrict__ nrm,
                                                   float* __restrict__ rs_g,
                                                   float* __restrict__ rp_g,
                                                   float* __restrict__ out) {
    const int gi = blockIdx.x * 256 + threadIdx.x;
    if (gi < B_ * T_) { rs_g[gi] = 0.0f; rp_g[gi] = 0.0f; }
    if (gi == 0) out[0] = 0.0f;

    const int row  = blockIdx.x * 4 + (threadIdx.x >> 6);
    const int lane = threadIdx.x & 63;
    const size_t off = (size_t)row * D_ + lane * 8;
    const float4 v0 = *(const float4*)(f + off);
    const float4 v1 = *(const float4*)(f + off + 4);
    float ss = v0.x*v0.x + v0.y*v0.y + v0.z*v0.z + v0.w*v0.w
             + v1.x*v1.x + v1.y*v1.y + v1.z*v1.z + v1.w*v1.w;
    #pragma unroll
    for (int o = 32; o >= 1; o >>= 1) ss += __shfl_xor(ss, o, 64);
    const float sc = 16.0f / fmaxf(sqrtf(ss), EPS_);   // pre-scale by 16
    unsigned int w0 =  (unsigned int)f2e4m3(v0.x*sc)
                    | ((unsigned int)f2e4m3(v0.y*sc) << 8)
                    | ((unsigned int)f2e4m3(v0.z*sc) << 16)
                    | ((unsigned int)f2e4m3(v0.w*sc) << 24);
    unsigned int w1 =  (unsigned int)f2e4m3(v1.x*sc)
                    | ((unsigned int)f2e4m3(v1.y*sc) << 8)
                    | ((unsigned int)f2e4m3(v1.z*sc) << 16)
                    | ((unsigned int)f2e4m3(v1.w*sc) << 24);
    uint2 w; w.x = w0; w.y = w1;
    *(uint2*)(nrm + (size_t)row * D_ + lane * 8) = w;   // 8 fp8 bytes/lane
}

// ---------------- MX-fp8 MFMA sim-GEMM: symmetric pairs, 4 waves = 128x128 ---
// v3: the r0-proven glds ring + barrier schedule + XOR chunk swizzle, scaled to
// a 128x128 tile per 256-thread block. Wave w owns quadrant (wr=w>>1, wc=w&1)
// = 64x64. Staging: stage S = [128 rows][64 B] of A and (off-diag) B; wave w
// DMAs row-groups {2w, 2w+1} (16 rows x 64 B = 1 KiB each). Ring of 4 slots,
// kit j consumes stages 2j,2j+1 and prefetches 2j+2,2j+3 after the barrier.
// A/B rows are each consumed by TWO quadrants -> staging bytes per MFMA halved
// vs the 64x64 version. Diag blocks: quadrant (1,0) is the transpose of (0,1)
// -> its wave stages/barriers but skips compute+epilogue.
__global__ __launch_bounds__(256, 2) void loss_kernel(const unsigned char* __restrict__ nrm,
                                                      float* __restrict__ rs_g,
                                                      float* __restrict__ rp_g) {
    const int slot = blockIdx.x & 15;
    int u = blockIdx.x >> 4;                        // pair index 0..35
    const int b = ((slot & 7) << 1) | (slot >> 3);  // XCD-pinned batches
    int bi = 0, rem = NB2;
    while (u >= rem) { u -= rem; --rem; ++bi; }
    const int bj   = bi + u;
    const bool diag = (bi == bj);

    const int t0 = bi * BT2;
    const int j0 = bj * BT2;
    const char* base = (const char*)(nrm + (size_t)b * T_ * D_);  // row = 512 B

    __shared__ __align__(16) char Ar[4][8192];   // 4-slot ring: [128 rows][64 B]
    __shared__ __align__(16) char Br[4][8192];

    const int l  = threadIdx.x & 63;
    const int w  = threadIdx.x >> 6;             // wave id 0..3
    const int wr = w >> 1;                       // quadrant row (0/1)
    const int wc = w & 1;                        // quadrant col (0/1)
    const int m  = l & 15;
    const bool dead = diag && (w == 2);          // (1,0) of a diag block

    // ---- staging (write-side swizzle, r0-identical per 16-row group):
    //      lane l -> row r=l>>2 of the group, phys chunk l&3 holds global
    //      chunk (l&3)^((r>>1)&3). Wave w covers groups 2w and 2w+1.
    const int r   = l >> 2;
    const int gsw = (l & 3) ^ ((r >> 1) & 3);
    const char* sAq[2];
    const char* sBq[2];
    #pragma unroll
    for (int q = 0; q < 2; ++q) {
        sAq[q] = base + (size_t)(t0 + (2 * w + q) * 16 + r) * 512 + gsw * 16;
        sBq[q] = base + (size_t)(j0 + (2 * w + q) * 16 + r) * 512 + gsw * 16;
    }

#define ISSUE(S) do {                                                      \
    _Pragma("unroll")                                                      \
    for (int q_ = 0; q_ < 2; ++q_)                                         \
        glds16(sAq[q_] + (S) * 64, Ar[(S) & 3] + (2 * w + q_) * 1024);     \
    if (!diag) {                                                           \
        _Pragma("unroll")                                                  \
        for (int q_ = 0; q_ < 2; ++q_)                                     \
            glds16(sBq[q_] + (S) * 64, Br[(S) & 3] + (2 * w + q_) * 1024); \
    }                                                                      \
} while (0)

    // ---- fragment reads (read-side swizzle, r0-identical within a group):
    //      lane (m, kq=l>>4) reads 32 B of row m from stage 2j+(kq>>1),
    //      phys chunks ph0, ph0^1 (XOR key (m>>1)&3). Quadrant selects groups
    //      wr*4+mi (A) / wc*4+ni (B).
    const int kqh = l >> 5;                      // stage select within kit
    const int ph0 = (2 * ((l >> 4) & 1)) ^ ((m >> 1) & 3);
    const int rd0 = m * 64 + ph0 * 16;
    const int rd1 = m * 64 + (ph0 ^ 1) * 16;

    floatx4 acc[4][4] = {};

    ISSUE(0); ISSUE(1);   // prologue: kit 0's two stages in flight

    #pragma unroll
    for (int j = 0; j < NKIT; ++j) {
        __syncthreads();                 // drain current-kit DMAs (all waves)
        if (j < NKIT - 1) { ISSUE(2 * j + 2); ISSUE(2 * j + 3); }

        if (!dead) {
            const char* As = Ar[(2 * j + kqh) & 3] + wr * 4096;
            const char* Bs = (diag ? Ar[(2 * j + kqh) & 3] : Br[(2 * j + kqh) & 3]) + wc * 4096;
            int8v af[4], bf[4];
            #pragma unroll
            for (int mi = 0; mi < 4; ++mi) {
                int4v lo = *(const int4v*)(As + mi * 1024 + rd0);
                int4v hi = *(const int4v*)(As + mi * 1024 + rd1);
                af[mi] = __builtin_shufflevector(lo, hi, 0, 1, 2, 3, 4, 5, 6, 7);
            }
            #pragma unroll
            for (int ni = 0; ni < 4; ++ni) {
                int4v lo = *(const int4v*)(Bs + ni * 1024 + rd0);
                int4v hi = *(const int4v*)(Bs + ni * 1024 + rd1);
                bf[ni] = __builtin_shufflevector(lo, hi, 0, 1, 2, 3, 4, 5, 6, 7);
            }
            #pragma unroll
            for (int mi = 0; mi < 4; ++mi)
                #pragma unroll
                for (int ni = 0; ni < 4; ++ni)
                    acc[mi][ni] = __builtin_amdgcn_mfma_scale_f32_16x16x128_f8f6f4(
                        af[mi], bf[ni], acc[mi][ni],
                        0, 0,              // cbsz=fp8(e4m3), blgp=fp8(e4m3)
                        0, SCL,            // opsel_a, scale_a (2^-4)
                        0, SCL);           // opsel_b, scale_b
        }
    }
#undef ISSUE

    if (dead) return;

    // Epilogue per quadrant. C/D layout (shape-determined, m89/m121-128):
    // col = lane&15, row = (lane>>4)*4 + reg. Verified r0 epilogue with
    // quadrant-local origins.
    const int t0q = t0 + wr * 64;
    const int j0q = j0 + wc * 64;
    const int d   = t0q - j0q;
    const bool nearq   = (d >= -64 && d <= 62);      // quadrant can hold j==t+1
    const bool cols_on = !(diag && (wr == wc));      // skip col-sums on diag subtiles
    const int lrow = l >> 4;
    const int lcol = l & 15;
    const int bT   = b * T_;
    float cs[4] = {0.f, 0.f, 0.f, 0.f};   // per-ni column partials

    #pragma unroll
    for (int mi = 0; mi < 4; ++mi) {
        #pragma unroll
        for (int rg = 0; rg < 4; ++rg) {
            const int t = t0q + mi * 16 + lrow * 4 + rg;
            float rsum = 0.f;
            #pragma unroll
            for (int ni = 0; ni < 4; ++ni) {
                const int j  = j0q + ni * 16 + lcol;
                const float s2 = acc[mi][ni][rg] * SCALE2;       // base-2 logit
                const float e  = exp2f(s2);
                if (j < t - 1 || j > t + 1) { rsum += e; cs[ni] += e; }
                if (nearq && j == t + 1) atomicAdd(&rp_g[bT + t], s2);  // unique owner
            }
            #pragma unroll
            for (int o = 8; o >= 1; o >>= 1) rsum += __shfl_xor(rsum, o, 64);
            if (lcol == 0) atomicAdd(&rs_g[bT + t], rsum);
        }
    }
    if (cols_on) {  // column sums: anchors j in J, negatives t in I (mask symmetric)
        #pragma unroll
        for (int ni = 0; ni < 4; ++ni) {
            float c = cs[ni];
            c += __shfl_xor(c, 16, 64);
            c += __shfl_xor(c, 32, 64);
            if (lrow == 0)
                atomicAdd(&rs_g[bT + j0q + ni * 16 + lcol], c);
        }
    }
}

// ---------------- finalize: loss per (b,t), mean (base-2 domain) -------------
__global__ __launch_bounds__(256) void fin_kernel(const float* __restrict__ rs_g,
                                                  const float* __restrict__ rp_g,
                                                  float* __restrict__ out) {
    const int idx = blockIdx.x * 256 + threadIdx.x;
    float v = 0.0f;
    if (idx < B_ * T_) {
        const int t = idx & (T_ - 1);
        if (t >= 1 && t <= T_ - 2) {
            const float p2 = rp_g[idx];           // pos logit * log2e
            const float s  = rs_g[idx];           // sum_neg 2^logit2
            v = (log2f(exp2f(p2) + s) - p2) * LN2_;
        }
    }
    #pragma unroll
    for (int o = 32; o >= 1; o >>= 1) v += __shfl_xor(v, o, 64);
    __shared__ float ws_[4];
    if ((threadIdx.x & 63) == 0) ws_[threadIdx.x >> 6] = v;
    __syncthreads();
    if (threadIdx.x == 0) {
        const float scale = 1.0f / (float)(B_ * (T_ - 2));
        atomicAdd(out, (ws_[0] + ws_[1] + ws_[2] + ws_[3]) * scale);
    }
}

extern "C" void kernel_launch(void* const* d_in, const int* in_sizes, int n_in,
                              void* d_out, int out_size, void* d_ws, size_t ws_size,
                              hipStream_t stream) {
    const float* feat = (const float*)d_in[0];
    float* out = (float*)d_out;

    // ws layout: nrm (fp8, B*T*D bytes = 8 MB) | rs (B*T f32) | rp (B*T f32)
    unsigned char* nrm = (unsigned char*)d_ws;
    float* rs_g = (float*)((char*)d_ws + (size_t)B_ * T_ * D_);
    float* rp_g = rs_g + B_ * T_;

    norm_kernel<<<B_ * T_ / 4, 256, 0, stream>>>(feat, nrm, rs_g, rp_g, out);
    loss_kernel<<<NPAIR2 * B_, 256, 0, stream>>>(nrm, rs_g, rp_g);
    fin_kernel<<<(B_ * T_ + 255) / 256, 256, 0, stream>>>(rs_g, rp_g, out);
}